// Round 7
// baseline (100.365 us; speedup 1.0000x reference)
//
#include <hip/hip_runtime.h>

// Problem constants: B=32, H=W=512
#define BATCH 32
#define HW 262144           // elements per image
#define HW4 65536           // float4 per image
#define W_IMG 512
#define N_BLOCKS 1024       // 32 batches * 32 bands (16 rows each)
#define N_BOX 96            // B * 3

// Workspace layout (doubles) — every slot written unconditionally, no init:
//  [0..1023]     per-block sum of output      (slot = batch*32 + band)
//  [1024..2047]  per-block sum of density
//  [2048..3071]  per-block sum of (o-d)^2
//  [3072..6143]  box partials: slot = box*32 + band  (96 boxes x 32 bands)
#define WS_SO   0
#define WS_SD   1024
#define WS_SQ   2048
#define WS_BOX  3072

__device__ __forceinline__ double wave_reduce_d(double v) {
    for (int off = 32; off > 0; off >>= 1)
        v += __shfl_down(v, off, 64);
    return v;
}

// Kernel 1: each block streams a 16-row band of one image, computing
// sum(o), sum(d), sum((o-d)^2), and partials of the 3 boxes of its batch.
// Load stream is software-pipelined in groups of 2 iterations (4 float4
// loads in flight ahead of compute) to cover memory latency; round-6's
// rolled loop only kept ~3 loads in flight at VGPR_Count=48.
__global__ __launch_bounds__(256) void fused_partials(const float4* __restrict__ o4,
                                                      const float4* __restrict__ d4,
                                                      const int* __restrict__ bb,
                                                      double* __restrict__ ws) {
    const int blk = blockIdx.x;
    const int batch = blk >> 5;
    const int band = blk & 31;                 // rows [band*16, band*16+16)
    const size_t base = (size_t)blk * 2048;    // float4 index
    const int t = threadIdx.x;
    const int col0 = (t & 127) * 4;            // constant per thread across iters
    const int rbase = band * 16 + (t >> 7);    // row at iter i = rbase + 2*i

    // Per-box precompute: column masks (constant per thread) + row range.
    float wm[3][4];
    int by1[3], by2[3];
    bool active[3];
#pragma unroll
    for (int k = 0; k < 3; ++k) {
        const int* p = bb + (batch * 3 + k) * 4;
        int x1 = min(max(p[0], 0), W_IMG);
        int y1 = min(max(p[1], 0), W_IMG);
        int x2 = min(max(p[2], 0), W_IMG);
        int y2 = min(max(p[3], 0), W_IMG);
        x2 = max(x2, x1);
        y2 = max(y2, y1);
        by1[k] = y1; by2[k] = y2;
#pragma unroll
        for (int j = 0; j < 4; ++j) {
            int c = col0 + j;
            wm[k][j] = (c >= x1 && c < x2) ? 1.0f : 0.0f;
        }
        active[k] = (y2 > band * 16) && (y1 < band * 16 + 16);  // block-uniform
    }

    double so = 0.0, sd = 0.0, ssq = 0.0;
    float bxs[3] = {0.0f, 0.0f, 0.0f};

    // Software pipeline: groups of 2 iterations; preload group g+1 while
    // accumulating group g.
    float4 ca[2], cb[2], na[2], nb[2];
#pragma unroll
    for (int j = 0; j < 2; ++j) {
        ca[j] = o4[base + t + j * 256];
        cb[j] = d4[base + t + j * 256];
    }

#pragma unroll
    for (int g = 0; g < 4; ++g) {
        if (g < 3) {
#pragma unroll
            for (int j = 0; j < 2; ++j) {
                na[j] = o4[base + t + (g * 2 + 2 + j) * 256];
                nb[j] = d4[base + t + (g * 2 + 2 + j) * 256];
            }
        }
#pragma unroll
        for (int j = 0; j < 2; ++j) {
            const float4 a = ca[j];
            const float4 b = cb[j];
            so += (double)a.x + (double)a.y + (double)a.z + (double)a.w;
            sd += (double)b.x + (double)b.y + (double)b.z + (double)b.w;
            double dx = (double)a.x - (double)b.x;
            double dy = (double)a.y - (double)b.y;
            double dz = (double)a.z - (double)b.z;
            double dw = (double)a.w - (double)b.w;
            ssq += dx * dx + dy * dy + dz * dz + dw * dw;

            const int row = rbase + 2 * (g * 2 + j);
#pragma unroll
            for (int k = 0; k < 3; ++k) {
                if (active[k]) {
                    float rok = (row >= by1[k] && row < by2[k]) ? 1.0f : 0.0f;
                    float s = a.x * wm[k][0] + a.y * wm[k][1] + a.z * wm[k][2] + a.w * wm[k][3];
                    bxs[k] = fmaf(rok, s, bxs[k]);
                }
            }
        }
#pragma unroll
        for (int j = 0; j < 2; ++j) { ca[j] = na[j]; cb[j] = nb[j]; }
    }

    // Block reduction of 6 quantities.
    const int lane = t & 63;
    const int wid = t >> 6;
    double b0 = (double)bxs[0], b1 = (double)bxs[1], b2 = (double)bxs[2];
    so = wave_reduce_d(so);
    sd = wave_reduce_d(sd);
    ssq = wave_reduce_d(ssq);
    b0 = wave_reduce_d(b0);
    b1 = wave_reduce_d(b1);
    b2 = wave_reduce_d(b2);

    __shared__ double sm[6][4];
    if (lane == 0) {
        sm[0][wid] = so; sm[1][wid] = sd; sm[2][wid] = ssq;
        sm[3][wid] = b0; sm[4][wid] = b1; sm[5][wid] = b2;
    }
    __syncthreads();
    if (t == 0) {
        ws[WS_SO + blk] = sm[0][0] + sm[0][1] + sm[0][2] + sm[0][3];
        ws[WS_SD + blk] = sm[1][0] + sm[1][1] + sm[1][2] + sm[1][3];
        ws[WS_SQ + blk] = sm[2][0] + sm[2][1] + sm[2][2] + sm[2][3];
#pragma unroll
        for (int k = 0; k < 3; ++k) {
            double bv = sm[3 + k][0] + sm[3 + k][1] + sm[3 + k][2] + sm[3 + k][3];
            ws[WS_BOX + (batch * 3 + k) * 32 + band] = bv;
        }
    }
}

// Kernel 2: finalize. 1 block, 256 threads.
__global__ __launch_bounds__(256) void finalize(const double* __restrict__ ws,
                                                const int* __restrict__ nobj,
                                                float* __restrict__ out) {
    const int t = threadIdx.x;
    const int lane = t & 63;
    const int wid = t >> 6;

    __shared__ double s_diff[32];  // per-batch (sum_o - sum_d)^2
    __shared__ double s_q[4];      // per-wave ssq partial
    __shared__ double s_m[4];      // per-wave min_count partial

    // count_loss: thread t sums slots [4t,4t+4); batch = t/8 (8 threads/batch)
    {
        double so4 = 0.0, sd4 = 0.0;
#pragma unroll
        for (int j = 0; j < 4; ++j) {
            so4 += ws[WS_SO + t * 4 + j];
            sd4 += ws[WS_SD + t * 4 + j];
        }
        for (int off = 4; off > 0; off >>= 1) {
            so4 += __shfl_down(so4, off, 8);
            sd4 += __shfl_down(sd4, off, 8);
        }
        if ((t & 7) == 0) {
            double d = so4 - sd4;
            s_diff[t >> 3] = d * d;
        }
    }

    // dmap ssq: thread t sums 4 slots, then full-wave reduce
    {
        double q = 0.0;
#pragma unroll
        for (int j = 0; j < 4; ++j) q += ws[WS_SQ + t * 4 + j];
        q = wave_reduce_d(q);
        if (lane == 0) s_q[wid] = q;
    }

    // min_count: 96 boxes x 32 bands; 8 threads/box x 4 slots, 3 passes of 32 boxes
    {
        double m = 0.0;
#pragma unroll
        for (int k = 0; k < 3; ++k) {
            int box = k * 32 + (t >> 3);
            double bs = 0.0;
#pragma unroll
            for (int j = 0; j < 4; ++j)
                bs += ws[WS_BOX + box * 32 + (t & 7) * 4 + j];
            for (int off = 4; off > 0; off >>= 1)
                bs += __shfl_down(bs, off, 8);
            if ((t & 7) == 0) {
                double r = 1.0 - bs;
                if (r > 0.0) m += r;
            }
        }
        m = wave_reduce_d(m);
        if (lane == 0) s_m[wid] = m;
    }

    __syncthreads();
    if (t == 0) {
        double cnt = 0.0;
        for (int i = 0; i < 32; ++i) cnt += s_diff[i];
        double q = s_q[0] + s_q[1] + s_q[2] + s_q[3];
        double m = s_m[0] + s_m[1] + s_m[2] + s_m[3];
        out[0] = (float)(q / (double)(*nobj));   // dmap_loss
        out[1] = (float)(cnt / (double)BATCH);   // count_loss
        out[2] = (float)m;                       // min_count
    }
}

extern "C" void kernel_launch(void* const* d_in, const int* in_sizes, int n_in,
                              void* d_out, int out_size, void* d_ws, size_t ws_size,
                              hipStream_t stream) {
    const float* output  = (const float*)d_in[0];
    const float* density = (const float*)d_in[1];
    const int*   bboxes  = (const int*)d_in[2];
    const int*   numobj  = (const int*)d_in[3];
    float* out = (float*)d_out;
    double* ws = (double*)d_ws;

    fused_partials<<<N_BLOCKS, 256, 0, stream>>>(
        (const float4*)output, (const float4*)density, bboxes, ws);

    finalize<<<1, 256, 0, stream>>>(ws, numobj, out);
}